// Round 6
// baseline (1739.722 us; speedup 1.0000x reference)
//
#include <hip/hip_runtime.h>
#include <hip/hip_bf16.h>

typedef unsigned short u16;
typedef unsigned int u32;
typedef unsigned long long u64;
typedef __attribute__((ext_vector_type(8))) __bf16 bf16x8;
typedef __attribute__((ext_vector_type(4))) float f32x4;

#define BB 64
#define TT 256
#define TE 128
#define EMB 512
#define RNN 1024
#define HID 128

// legacy-kernel constants
#define NKK 48
#define NEK 16
#define NHK 32
#define NBLK 128
#define HU 8

__device__ __forceinline__ u16 f2bf(float f) {
    u32 u = __float_as_uint(f);
    u32 r = (u + 0x7fffu + ((u >> 16) & 1u)) >> 16;
    return (u16)r;
}
__device__ __forceinline__ float bf2f(u16 h) { return __uint_as_float((u32)h << 16); }
__device__ __forceinline__ float sigm(float x) { return 1.f / (1.f + __expf(-x)); }
__device__ __forceinline__ float tanh_(float x) { return 2.f / (1.f + __expf(-2.f * x)) - 1.f; }

// 128-slot barrier (threads 0..63 each watch 2 slots); works for any blockDim >= 64
__device__ __forceinline__ void gbarL(u32* slots, unsigned phase) {
    __syncthreads();
    if (threadIdx.x == 0)
        __hip_atomic_store(&slots[blockIdx.x], phase, __ATOMIC_RELEASE,
                           __HIP_MEMORY_SCOPE_AGENT);
    if (threadIdx.x < 64) {
        const int l2 = (int)(threadIdx.x) * 2;
        while (__hip_atomic_load(&slots[l2], __ATOMIC_RELAXED, __HIP_MEMORY_SCOPE_AGENT) < phase ||
               __hip_atomic_load(&slots[l2 + 1], __ATOMIC_RELAXED, __HIP_MEMORY_SCOPE_AGENT) < phase) {
        }
        __builtin_amdgcn_fence(__ATOMIC_ACQUIRE, "agent");
    }
    __syncthreads();
}

// ---- scope-templated exchange ops: XL=1 -> intra-XCD (L2, sc0); XL=0 -> cross-XCD (sc0 sc1)
template<bool XL>
__device__ __forceinline__ u32 ld_flag(const u32* p) {
    u32 v;
    if (XL)
        asm volatile("global_load_dword %0, %1, off sc0\n\ts_waitcnt vmcnt(0)"
                     : "=v"(v) : "v"(p) : "memory");
    else
        asm volatile("global_load_dword %0, %1, off sc0 sc1\n\ts_waitcnt vmcnt(0)"
                     : "=v"(v) : "v"(p) : "memory");
    return v;
}
template<bool XL>
__device__ __forceinline__ void ld_slab(const u16* a0, const u16* a1, uint4& v0, uint4& v1) {
    if (XL)
        asm volatile("global_load_dwordx4 %0, %2, off sc0\n\t"
                     "global_load_dwordx4 %1, %3, off sc0\n\t"
                     "s_waitcnt vmcnt(0)"
                     : "=&v"(v0), "=&v"(v1) : "v"(a0), "v"(a1) : "memory");
    else
        asm volatile("global_load_dwordx4 %0, %2, off sc0 sc1\n\t"
                     "global_load_dwordx4 %1, %3, off sc0 sc1\n\t"
                     "s_waitcnt vmcnt(0)"
                     : "=&v"(v0), "=&v"(v1) : "v"(a0), "v"(a1) : "memory");
}
template<bool XL>
__device__ __forceinline__ void st_x(u32* p, u32 v) {
    if (XL)
        asm volatile("global_store_dword %0, %1, off sc0" :: "v"(p), "v"(v) : "memory");
    else
        asm volatile("global_store_dword %0, %1, off sc0 sc1" :: "v"(p), "v"(v) : "memory");
}

// ---------------- merged prep: gather_e | W_sw | U_sw (16-rank, 256-vcol layout) ----------
// blk <  2048          : gather e = bf16(emb[x]) rows [t*64+b][512]
// blk in [2048, 3072)  : W -> per-rank B-frags. r in 0..15, 16 tiles of 16 cols, K=512
// blk in [3072, 5120)  : U -> per-rank B-frags. r in 0..15, 16 tiles, K=1024
// vcol n in 0..255 maps to col = (n>>6)*RNN + r*64 + (n&63)   (gate*1024 + unit)
__global__ void __launch_bounds__(256) prep_all(const int* __restrict__ xi,
                                                const float* __restrict__ emb,
                                                const float* __restrict__ Wf,
                                                const float* __restrict__ Uf,
                                                u16* __restrict__ e_ws,
                                                u16* __restrict__ W_sw,
                                                u16* __restrict__ U_sw) {
    const int blk = blockIdx.x, tid = threadIdx.x;
    if (blk < 2048) {
        int row = blk * 4 + (tid >> 6);
        int lane = tid & 63;
        int t = row >> 6, b = row & 63;
        int tok = xi[b * TT + t];
        const float4* src = (const float4*)(emb + (size_t)tok * EMB + lane * 8);
        float4 v0 = src[0], v1 = src[1];
        u32 p0 = f2bf(v0.x) | ((u32)f2bf(v0.y) << 16);
        u32 p1 = f2bf(v0.z) | ((u32)f2bf(v0.w) << 16);
        u32 p2 = f2bf(v1.x) | ((u32)f2bf(v1.y) << 16);
        u32 p3 = f2bf(v1.z) | ((u32)f2bf(v1.w) << 16);
        uint4* dst = (uint4*)(e_ws + (size_t)row * EMB + lane * 8);
        *dst = make_uint4(p0, p1, p2, p3);
    } else if (blk < 3072) {
        int idx = (blk - 2048) * 256 + tid;   // 0..262143: 16r x 16kk x 16tile x 64lane
        int lane = idx & 63, tile = (idx >> 6) & 15, kk = (idx >> 10) & 15, r = idx >> 14;
        int n = tile * 16 + (lane & 15);                     // 0..255 virtual col
        int col = (n >> 6) * RNN + r * 64 + (n & 63);
        int kb = kk * 32 + ((lane >> 4) * 8);
        u16* dst = W_sw + (size_t)r * 131072 + (size_t)(kk * 16 + tile) * 512 + lane * 8;
#pragma unroll
        for (int j = 0; j < 8; j++) dst[j] = f2bf(Wf[(size_t)(kb + j) * 4096 + col]);
    } else {
        int idx = (blk - 3072) * 256 + tid;   // 0..524287: 16r x 32kk x 16tile x 64lane
        int lane = idx & 63, tile = (idx >> 6) & 15, kk = (idx >> 10) & 31, r = idx >> 15;
        int n = tile * 16 + (lane & 15);
        int col = (n >> 6) * RNN + r * 64 + (n & 63);
        int kb = kk * 32 + ((lane >> 4) * 8);
        u16* dst = U_sw + (size_t)r * 262144 + (size_t)(kk * 16 + tile) * 512 + lane * 8;
#pragma unroll
        for (int j = 0; j < 8; j++) dst[j] = f2bf(Uf[(size_t)(kb + j) * 4096 + col]);
    }
}

// ================= recurrent core (templated on exchange scope) =================
// group g owns batches [g*8, g*8+8); rank r owns units [r*64, r*64+64) x 4 gates.
// Flag protocol: data stores -> drain -> __syncthreads -> rank flag = t+1 (exact match).
// PROTOCOL STATE IS INITIALIZED IN-KERNEL each launch with the SAME scope ops as the
// exchange (iteration-safe: no reliance on host memset reaching XCD L2 copies).
template<bool XL>
__device__ void lstm_core(int g, int r, int tid,
                          const int* __restrict__ xi, const float* __restrict__ bvec,
                          const u16* __restrict__ e_ws, const u16* __restrict__ W_sw,
                          const u16* __restrict__ U_sw,
                          u16* __restrict__ hbuf, u32* __restrict__ flags,
                          u32* __restrict__ slots,
                          float* __restrict__ pooled,
                          u16* hsh, u16* esh, float* zsh) {
    const int lane = tid & 63, wv = tid >> 6;      // wv 0..7
    const int c = lane & 15, qd = lane >> 4;

    // ---- gate identity (active threads 0..255): batch b (0..7), unit pair 2q,2q+1 ----
    const bool act = tid < 256;
    const int b = (tid >> 5) & 7, q = tid & 31;
    const int bg = g * 8 + b;
    const int gu = r * 64 + 2 * q;

    // ---- IN-KERNEL protocol-state init (every launch): h(0)=0 in slot 0 + own flags=0 ----
    if (act) {
        u32* p0 = (u32*)(hbuf + (size_t)g * 8192 + (size_t)b * 1024 + gu);
        st_x<XL>(p0, 0u);
    }
    if (tid < 4) {
        u32* fp = flags + ((size_t)tid * 8 + g) * 16 + r;
        st_x<XL>(fp, 0u);
    }
    gbarL(slots, 2);   // all init stores drained (syncthreads inside drains vmcnt) + visible

    // ---- persistent U-slice in registers: 32 kk x 2 tiles per wave (128 VGPR) ----
    bf16x8 barr[64];
    {
        const u16* ub = U_sw + (size_t)r * 262144;
#pragma unroll
        for (int kk = 0; kk < 32; kk++) {
            barr[kk * 2 + 0] = *(const bf16x8*)(ub + (size_t)(kk * 16 + wv * 2 + 0) * 512 + lane * 8);
            barr[kk * 2 + 1] = *(const bf16x8*)(ub + (size_t)(kk * 16 + wv * 2 + 1) * 512 + lane * 8);
        }
    }
    const u16* wbase = W_sw + (size_t)r * 131072;

    float bI0 = 0.f, bI1 = 0.f, bF0 = 0.f, bF1 = 0.f;
    float bG0 = 0.f, bG1 = 0.f, bO0 = 0.f, bO1 = 0.f;
    u64 mlo = 0ull, mhi = 0ull;
    if (act) {
        bI0 = bvec[0 * RNN + gu]; bI1 = bvec[0 * RNN + gu + 1];
        bF0 = bvec[1 * RNN + gu]; bF1 = bvec[1 * RNN + gu + 1];
        bG0 = bvec[2 * RNN + gu]; bG1 = bvec[2 * RNN + gu + 1];
        bO0 = bvec[3 * RNN + gu]; bO1 = bvec[3 * RNN + gu + 1];
        for (int t = 0; t < 64; t++) mlo |= (u64)(xi[bg * TT + t] == 2) << t;
        for (int t = 64; t < TE; t++) mhi |= (u64)(xi[bg * TT + t] == 2) << (t - 64);
    }
    float cs0 = 0.f, cs1 = 0.f, pool0 = 0.f, pool1 = 0.f;

    // ---- preload e(0) into esh: 512 threads x 1 uint4 ----
    {
        const int eb = tid >> 6, ec = (tid & 63) * 8;
        *(uint4*)&esh[eb * 520 + ec] =
            *(const uint4*)(e_ws + (size_t)(g * 8 + eb) * EMB + ec);
    }
    __syncthreads();

    for (int t = 0; t < TE; t++) {
        // ---- z_e = e(t) @ W-slice (A from esh, B streamed from L2); 4 acc chains ----
        f32x4 ac00 = {0.f, 0.f, 0.f, 0.f}, ac01 = {0.f, 0.f, 0.f, 0.f};
        f32x4 ac10 = {0.f, 0.f, 0.f, 0.f}, ac11 = {0.f, 0.f, 0.f, 0.f};
#pragma unroll
        for (int kk = 0; kk < 16; kk++) {
            bf16x8 a = *(const bf16x8*)&esh[c * 520 + kk * 32 + qd * 8];
            bf16x8 b0 = *(const bf16x8*)(wbase + (size_t)(kk * 16 + wv * 2 + 0) * 512 + lane * 8);
            bf16x8 b1 = *(const bf16x8*)(wbase + (size_t)(kk * 16 + wv * 2 + 1) * 512 + lane * 8);
            if (kk & 1) {
                ac01 = __builtin_amdgcn_mfma_f32_16x16x32_bf16(a, b0, ac01, 0, 0, 0);
                ac11 = __builtin_amdgcn_mfma_f32_16x16x32_bf16(a, b1, ac11, 0, 0, 0);
            } else {
                ac00 = __builtin_amdgcn_mfma_f32_16x16x32_bf16(a, b0, ac00, 0, 0, 0);
                ac10 = __builtin_amdgcn_mfma_f32_16x16x32_bf16(a, b1, ac10, 0, 0, 0);
            }
        }

        // ---- prefetch e(t+1) into regs ----
        const int tn = (t + 1 < TE) ? (t + 1) : t;
        uint4 ep;
        {
            const int eb = tid >> 6, ec = (tid & 63) * 8;
            ep = *(const uint4*)(e_ws + (size_t)(tn * 64 + g * 8 + eb) * EMB + ec);
        }

        // ---- wait for h(t): poll 16 per-rank flags (exact value t, bounded) ----
        {
            const u32 want = (u32)t;
            const u32* fp = flags + ((size_t)(t & 3) * 8 + g) * 16 + (tid & 15);
            int guard = 1 << 16;
            for (;;) {
                u32 fv = ld_flag<XL>(fp);
                if (fv == want) break;
                if (--guard == 0) break;   // fail visibly within bounded time
                __builtin_amdgcn_s_sleep(1);
            }
        }
        __syncthreads();   // all 16 flags seen -> whole slab committed

        // ---- single bulk read of the group's h slab (8 x 2048B = 16KB) ----
        const u16* hb = hbuf + (size_t)(t & 3) * 65536 + (size_t)g * 8192;
        uint4 v0, v1;
        ld_slab<XL>(hb + tid * 8, hb + 4096 + tid * 8, v0, v1);

        // ---- stage h into LDS: rows tid>>7 and 4+(tid>>7), cols (tid&127)*8 ----
        {
            const int rr = tid >> 7, col = (tid & 127) * 8;
            *(uint4*)&hsh[(0 + rr) * 1032 + col] = v0;
            *(uint4*)&hsh[(4 + rr) * 1032 + col] = v1;
        }
        __syncthreads();

        // ---- esh <- e(t+1) ----
        {
            const int eb = tid >> 6, ec = (tid & 63) * 8;
            *(uint4*)&esh[eb * 520 + ec] = ep;
        }

        // ---- z_h = h @ U-slice (B in registers); A rows 8..15 junk, C rows 8..15 discarded --
#pragma unroll
        for (int kk = 0; kk < 32; kk++) {
            bf16x8 a = *(const bf16x8*)&hsh[c * 1032 + kk * 32 + qd * 8];
            if (kk & 1) {
                ac01 = __builtin_amdgcn_mfma_f32_16x16x32_bf16(a, barr[kk * 2 + 0], ac01, 0, 0, 0);
                ac11 = __builtin_amdgcn_mfma_f32_16x16x32_bf16(a, barr[kk * 2 + 1], ac11, 0, 0, 0);
            } else {
                ac00 = __builtin_amdgcn_mfma_f32_16x16x32_bf16(a, barr[kk * 2 + 0], ac00, 0, 0, 0);
                ac10 = __builtin_amdgcn_mfma_f32_16x16x32_bf16(a, barr[kk * 2 + 1], ac10, 0, 0, 0);
            }
        }
        {
            f32x4 acc0 = ac00 + ac01;
            f32x4 acc1 = ac10 + ac11;
            if (qd < 2) {    // C rows 0..7 = real batches
#pragma unroll
                for (int reg = 0; reg < 4; reg++) {
                    zsh[(qd * 4 + reg) * 260 + (wv * 2 + 0) * 16 + c] = acc0[reg];
                    zsh[(qd * 4 + reg) * 260 + (wv * 2 + 1) * 16 + c] = acc1[reg];
                }
            }
        }
        __syncthreads();

        // ---- gates + publish (active threads) ----
        if (act) {
            const float* zrow = &zsh[b * 260];
            const int u0 = 2 * q;
            float h0, h1;
            {
                float zi = zrow[u0] + bI0;
                float zf = zrow[64 + u0] + bF0;
                float zg = zrow[128 + u0] + bG0;
                float zo = zrow[192 + u0] + bO0;
                float cn = sigm(zf) * cs0 + sigm(zi) * tanh_(zg);
                h0 = sigm(zo) * tanh_(cn);
                cs0 = cn;
            }
            {
                float zi = zrow[u0 + 1] + bI1;
                float zf = zrow[64 + u0 + 1] + bF1;
                float zg = zrow[128 + u0 + 1] + bG1;
                float zo = zrow[192 + u0 + 1] + bO1;
                float cn = sigm(zf) * cs1 + sigm(zi) * tanh_(zg);
                h1 = sigm(zo) * tanh_(cn);
                cs1 = cn;
            }
            u64 mm = (t < 64) ? mlo : mhi;
            if ((mm >> (t & 63)) & 1) { pool0 += h0; pool1 += h1; }

            u32 hw = (u32)f2bf(h0) | ((u32)f2bf(h1) << 16);
            u32* pubp = (u32*)(hbuf + (size_t)((t + 1) & 3) * 65536 +
                               (size_t)g * 8192 + (size_t)b * 1024 + gu);
            st_x<XL>(pubp, hw);
        }
        __syncthreads();     // implicit vmcnt drain: all 256 data stores committed
        if (tid == 0) {
            u32* fgp = flags + ((size_t)((t + 1) & 3) * 8 + g) * 16 + r;
            st_x<XL>(fgp, (u32)(t + 1));
        }
    }

    if (act) {
        __hip_atomic_store(&pooled[(size_t)bg * RNN + gu], pool0,
                           __ATOMIC_RELAXED, __HIP_MEMORY_SCOPE_AGENT);
        __hip_atomic_store(&pooled[(size_t)bg * RNN + gu + 1], pool1,
                           __ATOMIC_RELAXED, __HIP_MEMORY_SCOPE_AGENT);
    }
}

// ================= 128-block x 512-thread persistent LSTM, XCD-local groups =================
__global__ void __launch_bounds__(512, 1) lstm_x16(
    const int* __restrict__ xi, const float* __restrict__ bvec,
    const float* __restrict__ W1, const float* __restrict__ bias1,
    const float* __restrict__ W2, const float* __restrict__ bias2,
    const float* __restrict__ Wc, const float* __restrict__ biasc,
    const u16* __restrict__ e_ws, const u16* __restrict__ W_sw,
    const u16* __restrict__ U_sw,
    u16* __restrict__ hbufA, u16* __restrict__ hbufB,
    u32* __restrict__ flagsA, u32* __restrict__ flagsB,
    u32* __restrict__ slots, u32* __restrict__ xcd_of,
    float* __restrict__ pooled, float* __restrict__ h1_ws, float* __restrict__ h2_ws,
    float* __restrict__ outp) {
    __shared__ u16 hsh[16 * 1032];      // 33024 B (rows 8..15 never written; junk ok)
    __shared__ u16 esh[16 * 520];       // 16640 B (rows 8..15 junk ok)
    __shared__ float zsh[8 * 260];      //  8320 B
    __shared__ u32 xsh[128];
    __shared__ u32 bcast[4];
    __shared__ u32 lds_pad[5888];       // 23552 B -> total ~82 KB -> 1 block/CU

    const int tid = threadIdx.x, blk = blockIdx.x;
    {
        volatile u32* vp = lds_pad;
        vp[tid & 4095] = 0u;
    }

    // ---- election: expect 16 blocks per physical XCD ----
    if (tid == 0) {
        u32 x = __builtin_amdgcn_s_getreg(63508) & 7u;   // HW_REG_XCC_ID
        __hip_atomic_store(&xcd_of[blk], x, __ATOMIC_RELEASE, __HIP_MEMORY_SCOPE_AGENT);
    }
    gbarL(slots, 1);
    if (tid < 128)
        xsh[tid] = __hip_atomic_load(&xcd_of[tid], __ATOMIC_RELAXED, __HIP_MEMORY_SCOPE_AGENT);
    __syncthreads();
    if (tid == 0) {
        int cnt[8] = {0, 0, 0, 0, 0, 0, 0, 0};
        int rank = 0;
        u32 mine = xsh[blk] & 7;
        for (int i = 0; i < 128; i++) {
            u32 xv = xsh[i] & 7;
            cnt[xv]++;
            if (i < blk && xv == mine) rank++;
        }
        int ok = 1;
        for (int j = 0; j < 8; j++) ok &= (cnt[j] == 16);
        bcast[0] = (u32)ok;
        bcast[1] = ok ? mine : (u32)(blk >> 4);
        bcast[2] = ok ? (u32)rank : (u32)(blk & 15);
    }
    __syncthreads();
    const int fastm = (int)bcast[0];
    const int g = (int)bcast[1];
    const int r = (int)bcast[2];

    // mode-separated protocol regions: fastm never shares lines with the sc1 path
    if (fastm)
        lstm_core<true>(g, r, tid, xi, bvec, e_ws, W_sw, U_sw, hbufA, flagsA, slots,
                        pooled, hsh, esh, zsh);
    else
        lstm_core<false>(g, r, tid, xi, bvec, e_ws, W_sw, U_sw, hbufB, flagsB, slots,
                         pooled, hsh, esh, zsh);

    gbarL(slots, 3);

    // ---- MLP stage 1 (j = blk; threads 0..255: m = tid>>2, quarter qq) ----
    if (tid < 256) {
        int j = blk, m = tid >> 2, qq = tid & 3;
        float s = 0.f;
        const float* prow = pooled + (size_t)m * RNN;
#pragma unroll 4
        for (int k = qq * 256; k < qq * 256 + 256; k++)
            s += prow[k] * W1[(size_t)k * HID + j];
        s += __shfl_xor(s, 1);
        s += __shfl_xor(s, 2);
        if (qq == 0)
            __hip_atomic_store(&h1_ws[m * HID + j], fmaxf(s + bias1[j], 0.f),
                               __ATOMIC_RELAXED, __HIP_MEMORY_SCOPE_AGENT);
    }
    gbarL(slots, 4);

    // ---- MLP stage 2 ----
    if (tid < 256) {
        int j = blk, m = tid >> 2, qq = tid & 3;
        float s = 0.f;
        const float* hrow1 = h1_ws + m * HID;
#pragma unroll 4
        for (int k = qq * 32; k < qq * 32 + 32; k++)
            s += hrow1[k] * W2[(size_t)k * HID + j];
        s += __shfl_xor(s, 1);
        s += __shfl_xor(s, 2);
        if (qq == 0)
            __hip_atomic_store(&h2_ws[m * HID + j], fmaxf(s + bias2[j], 0.f),
                               __ATOMIC_RELAXED, __HIP_MEMORY_SCOPE_AGENT);
    }
    gbarL(slots, 5);

    // ---- logits + softmax ----
    if (blk == 0 && tid < 256) {
        int m = tid >> 2, lb = tid & 3;
        float s = 0.f;
        const float* hrow2 = h2_ws + m * HID;
#pragma unroll 4
        for (int k = 0; k < HID; k++) s += hrow2[k] * Wc[k * 4 + lb];
        s += biasc[lb];
        float mx = fmaxf(s, __shfl_xor(s, 1));
        mx = fmaxf(mx, __shfl_xor(mx, 2));
        float e = __expf(s - mx);
        float den = e + __shfl_xor(e, 1);
        den += __shfl_xor(den, 2);
        outp[m * 4 + lb] = e / den;
    }
}

// ================= legacy kernel (last-ditch fallback, proven) =================
__global__ void __launch_bounds__(256, 1) lstm_legacy(
    const int* __restrict__ xi, const float* __restrict__ Wf, const float* __restrict__ Uf,
    const float* __restrict__ bvec, const float* __restrict__ W1, const float* __restrict__ bias1,
    const float* __restrict__ W2, const float* __restrict__ bias2, const float* __restrict__ Wc,
    const float* __restrict__ biasc, const u16* __restrict__ e_ws, u16* __restrict__ hbuf,
    u32* __restrict__ slots, float* __restrict__ pooled_ws, float* __restrict__ h1_ws,
    float* __restrict__ h2_ws, float* __restrict__ outp) {
    __shared__ __align__(16) u16 bsh[NKK][2][64][8];
    __shared__ float zshL[64][33];

    const int tid = threadIdx.x;
    const int blk = blockIdx.x;
    const int n0 = blk * HU;
    const int wv = tid >> 6, lane = tid & 63;

    for (int slot = tid; slot < NKK * 2 * 64; slot += 256) {
        int l = slot & 63, tl = (slot >> 6) & 1, kk = slot >> 7;
        int n = tl * 16 + (l & 15);
        int col = (n >> 3) * RNN + n0 + (n & 7);
        int kbase = kk * 32 + ((l >> 4) * 8);
        u16* dst = &bsh[kk][tl][l][0];
#pragma unroll
        for (int j = 0; j < 8; j++) {
            int k = kbase + j;
            float v = (k < EMB) ? Wf[(size_t)k * 4096 + col]
                                : Uf[(size_t)(k - EMB) * 4096 + col];
            dst[j] = f2bf(v);
        }
    }

    const int em = tid >> 2;
    const int eu2 = tid & 3;
    float cst0 = 0.f, cst1 = 0.f, pool0 = 0.f, pool1 = 0.f;
    float bias[4][2];
#pragma unroll
    for (int gg = 0; gg < 4; gg++) {
        bias[gg][0] = bvec[gg * RNN + n0 + eu2 * 2];
        bias[gg][1] = bvec[gg * RNN + n0 + eu2 * 2 + 1];
    }
    u64 m2lo = 0ull, m2hi = 0ull;
    for (int t = 0; t < 64; t++) m2lo |= (u64)(xi[em * TT + t] == 2) << t;
    for (int t = 64; t < TE; t++) m2hi |= (u64)(xi[em * TT + t] == 2) << (t - 64);
    __syncthreads();

    const int mrow = wv * 16 + (lane & 15);
    const int kq = (lane >> 4) * 8;
    u16* const hb0 = hbuf;
    u16* const hb1 = hbuf + BB * RNN;
    unsigned phase = 0;

    bf16x8 epf[NEK];
    {
        const u16* erow = e_ws + ((size_t)mrow) * EMB + kq;
#pragma unroll
        for (int i = 0; i < NEK; i++) epf[i] = *(const bf16x8*)(erow + i * 32);
    }

    for (int t = 0; t < TE; t++) {
        const u16* hin = (t & 1) ? hb1 : hb0;
        u16* hout = (t & 1) ? hb0 : hb1;
        const u16* hrow = hin + (size_t)mrow * RNN + kq;

        bf16x8 fr[NHK];
#pragma unroll
        for (int i = 0; i < NHK; i++) fr[i] = *(const bf16x8*)(hrow + i * 32);

        f32x4 acc0 = {0.f, 0.f, 0.f, 0.f}, acc1 = {0.f, 0.f, 0.f, 0.f};
#pragma unroll
        for (int kk = 0; kk < NEK; kk++) {
            bf16x8 b0 = *(const bf16x8*)&bsh[kk][0][lane][0];
            bf16x8 b1 = *(const bf16x8*)&bsh[kk][1][lane][0];
            acc0 = __builtin_amdgcn_mfma_f32_16x16x32_bf16(epf[kk], b0, acc0, 0, 0, 0);
            acc1 = __builtin_amdgcn_mfma_f32_16x16x32_bf16(epf[kk], b1, acc1, 0, 0, 0);
        }
#pragma unroll
        for (int kk = 0; kk < NHK; kk++) {
            bf16x8 b0 = *(const bf16x8*)&bsh[NEK + kk][0][lane][0];
            bf16x8 b1 = *(const bf16x8*)&bsh[NEK + kk][1][lane][0];
            acc0 = __builtin_amdgcn_mfma_f32_16x16x32_bf16(fr[kk], b0, acc0, 0, 0, 0);
            acc1 = __builtin_amdgcn_mfma_f32_16x16x32_bf16(fr[kk], b1, acc1, 0, 0, 0);
        }
        if (t + 1 < TE) {
            const u16* erow = e_ws + ((size_t)((t + 1) * BB + mrow)) * EMB + kq;
#pragma unroll
            for (int i = 0; i < NEK; i++) epf[i] = *(const bf16x8*)(erow + i * 32);
        }
        {
            int crow = wv * 16 + ((lane >> 4) * 4);
            int ccol = lane & 15;
#pragma unroll
            for (int reg = 0; reg < 4; reg++) {
                zshL[crow + reg][ccol] = acc0[reg];
                zshL[crow + reg][16 + ccol] = acc1[reg];
            }
        }
        __syncthreads();

        int is2 = (t < 64) ? (int)((m2lo >> t) & 1) : (int)((m2hi >> (t - 64)) & 1);
        float hn0, hn1;
        {
            int uu = eu2 * 2;
            float zi = zshL[em][uu] + bias[0][0];
            float zf = zshL[em][8 + uu] + bias[1][0];
            float zg = zshL[em][16 + uu] + bias[2][0];
            float zo = zshL[em][24 + uu] + bias[3][0];
            float cn = sigm(zf) * cst0 + sigm(zi) * tanh_(zg);
            hn0 = sigm(zo) * tanh_(cn);
            cst0 = cn;
            if (is2) pool0 += hn0;
        }
        {
            int uu = eu2 * 2 + 1;
            float zi = zshL[em][uu] + bias[0][1];
            float zf = zshL[em][8 + uu] + bias[1][1];
            float zg = zshL[em][16 + uu] + bias[2][1];
            float zo = zshL[em][24 + uu] + bias[3][1];
            float cn = sigm(zf) * cst1 + sigm(zi) * tanh_(zg);
            hn1 = sigm(zo) * tanh_(cn);
            cst1 = cn;
            if (is2) pool1 += hn1;
        }
        u32 hw = (u32)f2bf(hn0) | ((u32)f2bf(hn1) << 16);
        __hip_atomic_store((u32*)(hout + (size_t)em * RNN + n0 + eu2 * 2), hw,
                           __ATOMIC_RELAXED, __HIP_MEMORY_SCOPE_AGENT);
        gbarL(slots, ++phase);
    }

    __hip_atomic_store(&pooled_ws[em * RNN + n0 + eu2 * 2], pool0,
                       __ATOMIC_RELAXED, __HIP_MEMORY_SCOPE_AGENT);
    __hip_atomic_store(&pooled_ws[em * RNN + n0 + eu2 * 2 + 1], pool1,
                       __ATOMIC_RELAXED, __HIP_MEMORY_SCOPE_AGENT);
    gbarL(slots, ++phase);

    {
        int j = blk, m = tid >> 2, qq = tid & 3;
        float s = 0.f;
        const float* prow = pooled_ws + m * RNN;
#pragma unroll 4
        for (int k = qq * 256; k < qq * 256 + 256; k++)
            s += prow[k] * W1[(size_t)k * HID + j];
        s += __shfl_xor(s, 1);
        s += __shfl_xor(s, 2);
        if (qq == 0)
            __hip_atomic_store(&h1_ws[m * HID + j], fmaxf(s + bias1[j], 0.f),
                               __ATOMIC_RELAXED, __HIP_MEMORY_SCOPE_AGENT);
    }
    gbarL(slots, ++phase);
    {
        int j = blk, m = tid >> 2, qq = tid & 3;
        float s = 0.f;
        const float* hrow1 = h1_ws + m * HID;
#pragma unroll 4
        for (int k = qq * 32; k < qq * 32 + 32; k++)
            s += hrow1[k] * W2[(size_t)k * HID + j];
        s += __shfl_xor(s, 1);
        s += __shfl_xor(s, 2);
        if (qq == 0)
            __hip_atomic_store(&h2_ws[m * HID + j], fmaxf(s + bias2[j], 0.f),
                               __ATOMIC_RELAXED, __HIP_MEMORY_SCOPE_AGENT);
    }
    gbarL(slots, ++phase);
    if (blk == 0) {
        int m = tid >> 2, lb = tid & 3;
        float s = 0.f;
        const float* hrow2 = h2_ws + m * HID;
#pragma unroll 4
        for (int k = 0; k < HID; k++) s += hrow2[k] * Wc[k * 4 + lb];
        s += biasc[lb];
        float mx = fmaxf(s, __shfl_xor(s, 1));
        mx = fmaxf(mx, __shfl_xor(mx, 2));
        float e = __expf(s - mx);
        float den = e + __shfl_xor(e, 1);
        den += __shfl_xor(den, 2);
        outp[m * 4 + lb] = e / den;
    }
}

extern "C" void kernel_launch(void* const* d_in, const int* in_sizes, int n_in,
                              void* d_out, int out_size, void* d_ws, size_t ws_size,
                              hipStream_t stream) {
    (void)in_sizes; (void)n_in; (void)out_size;
    const int* xi = (const int*)d_in[0];
    const float* emb = (const float*)d_in[1];
    const float* Wf = (const float*)d_in[2];
    const float* Uf = (const float*)d_in[3];
    const float* bvec = (const float*)d_in[4];
    const float* W1 = (const float*)d_in[5];
    const float* b1 = (const float*)d_in[6];
    const float* W2 = (const float*)d_in[7];
    const float* b2 = (const float*)d_in[8];
    const float* Wc = (const float*)d_in[9];
    const float* bc = (const float*)d_in[10];
    float* outp = (float*)d_out;
    char* w = (char*)d_ws;

    // e_ws 8M | U_sw 8M | W_sw 4M | hbufA 512K | hbufB 512K | hbufC 256K
    // | flagsA 4K | flagsB 4K | slots 1K | xcdof 1K | pooled 256K | h1 32K | h2 32K
    const size_t NEED = 22620160;
    bool newpath = (ws_size >= NEED);

    if (newpath) {
        u16* e_ws   = (u16*)(w + 0);                   // 8 MB
        u16* U_sw   = (u16*)(w + 8388608);             // 8 MB
        u16* W_sw   = (u16*)(w + 16777216);            // 4 MB
        u16* hbufA  = (u16*)(w + 20971520);            // 512 KB (fastm, sc0/L2-resident)
        u16* hbufB  = (u16*)(w + 21495808);            // 512 KB (cross-XCD, sc0 sc1)
        u16* hbufC  = (u16*)(w + 22020096);            // 256 KB (legacy only)
        u32* flagsA = (u32*)(w + 22282240);            // 4 KB
        u32* flagsB = (u32*)(w + 22286336);            // 4 KB
        u32* slots  = (u32*)(w + 22290432);            // 1 KB
        u32* xcdof  = (u32*)(w + 22291456);            // 1 KB
        float* pooled = (float*)(w + 22292480);        // 256 KB
        float* h1_ws  = (float*)(w + 22554624);        // 32 KB
        float* h2_ws  = (float*)(w + 22587392);        // 32 KB

        hipMemsetAsync(slots, 0, 2048, stream);        // slots + xcdof (protocol state is
                                                       // initialized IN-KERNEL each launch)
        hipMemsetAsync(hbufC, 0, 131072, stream);      // legacy hb0 = h(0) = 0

        prep_all<<<dim3(5120), dim3(256), 0, stream>>>(xi, emb, Wf, Uf, e_ws, W_sw, U_sw);

        int occ = 0;
        hipError_t qe = hipOccupancyMaxActiveBlocksPerMultiprocessor(
            &occ, (const void*)lstm_x16, 512, 0);
        (void)hipGetLastError();
        bool tryNew = (qe == hipSuccess && occ >= 1);

        hipError_t le = hipErrorUnknown;
        if (tryNew) {
            void* args[] = {(void*)&xi, (void*)&bvec, (void*)&W1, (void*)&b1, (void*)&W2,
                            (void*)&b2, (void*)&Wc, (void*)&bc, (void*)&e_ws, (void*)&W_sw,
                            (void*)&U_sw, (void*)&hbufA, (void*)&hbufB, (void*)&flagsA,
                            (void*)&flagsB, (void*)&slots, (void*)&xcdof, (void*)&pooled,
                            (void*)&h1_ws, (void*)&h2_ws, (void*)&outp};
            le = hipLaunchCooperativeKernel((void*)lstm_x16, dim3(NBLK), dim3(512),
                                            args, 0, stream);
            if (le != hipSuccess) (void)hipGetLastError();
        }
        if (le != hipSuccess) {
            // legacy fallback on its own never-sc0 region
            void* argsL[] = {(void*)&xi, (void*)&Wf, (void*)&Uf, (void*)&bvec, (void*)&W1,
                             (void*)&b1, (void*)&W2, (void*)&b2, (void*)&Wc, (void*)&bc,
                             (void*)&e_ws, (void*)&hbufC, (void*)&slots, (void*)&pooled,
                             (void*)&h1_ws, (void*)&h2_ws, (void*)&outp};
            hipError_t l2 = hipLaunchCooperativeKernel((void*)lstm_legacy, dim3(NBLK), dim3(256),
                                                       argsL, 0, stream);
            (void)l2;
        }
        return;
    }

    // ---- small-workspace path: original legacy layout ----
    {
        u16* e_ws = (u16*)w;
        u16* hbuf = (u16*)(w + 8388608);
        u32* slots = (u32*)(w + 8388608 + 262144);
        float* pooled_ws = (float*)(w + 8388608 + 263168);
        float* h1_ws = (float*)(w + 8388608 + 263168 + 262144);
        float* h2_ws = (float*)(w + 8388608 + 263168 + 262144 + 32768);

        hipMemsetAsync(hbuf, 0, 262144 + 1024, stream);
        prep_all<<<dim3(2048), dim3(256), 0, stream>>>(xi, emb, Wf, Uf, e_ws,
                                                       (u16*)(w), (u16*)(w));  // only blk<2048 writes
        void* args[] = {(void*)&xi, (void*)&Wf, (void*)&Uf, (void*)&bvec, (void*)&W1,
                        (void*)&b1, (void*)&W2, (void*)&b2, (void*)&Wc, (void*)&bc,
                        (void*)&e_ws, (void*)&hbuf, (void*)&slots, (void*)&pooled_ws,
                        (void*)&h1_ws, (void*)&h2_ws, (void*)&outp};
        hipError_t le = hipLaunchCooperativeKernel((void*)lstm_legacy, dim3(NBLK), dim3(256),
                                                   args, 0, stream);
        (void)le;
    }
}